// Round 9
// baseline (129.549 us; speedup 1.0000x reference)
//
#include <hip/hip_runtime.h>

constexpr int NB = 8;
constexpr int NN = 8192;
constexpr int NH = 128;
constexpr int NG = 16;
constexpr int NT = 36;            // table intervals per axis
constexpr int NT1 = NT + 1;       // 37 grid points
constexpr int NGRP = NB * NN / 16; // 4096 groups of 16 nodes

typedef short s16x8 __attribute__((ext_vector_type(8)));
typedef float f32x4 __attribute__((ext_vector_type(4)));

__device__ __forceinline__ float frcp(float x) { return __builtin_amdgcn_rcpf(x); }
__device__ __forceinline__ float frsq(float x) { return __builtin_amdgcn_rsqf(x); }
__device__ __forceinline__ float fsigmoid(float x) { return frcp(1.f + __expf(-x)); }
__device__ __forceinline__ float fsilu(float x) { return x * fsigmoid(x); }
__device__ __forceinline__ float fclamp1(float x) { return fminf(fmaxf(x, -1.f), 1.f); }

__device__ __forceinline__ unsigned short f2bf(float x) {  // f32 -> bf16 RTNE
    unsigned u = __builtin_bit_cast(unsigned, x);
    return (unsigned short)((u + 0x7FFFu + ((u >> 16) & 1u)) >> 16);
}
__device__ __forceinline__ unsigned packh2(float a, float b) {
    unsigned short lo = __builtin_bit_cast(unsigned short, (__fp16)a);
    unsigned short hi = __builtin_bit_cast(unsigned short, (__fp16)b);
    return (unsigned)lo | ((unsigned)hi << 16);
}
__device__ __forceinline__ float h2lo(unsigned u) {
    return (float)__builtin_bit_cast(__fp16, (unsigned short)(u & 0xFFFFu));
}
__device__ __forceinline__ float h2hi(unsigned u) {
    return (float)__builtin_bit_cast(__fp16, (unsigned short)(u >> 16));
}

// ---------------- K0: build NT1 x NT1 bilinear table of both gate MLPs ------
__global__ __launch_bounds__(256) void k_table(
    const float* __restrict__ qw1, const float* __restrict__ qb1,
    const float* __restrict__ qw2, const float* __restrict__ qb2,
    const float* __restrict__ kw1, const float* __restrict__ kb1,
    const float* __restrict__ kw2, const float* __restrict__ kb2,
    unsigned* __restrict__ T) {
    int idx = blockIdx.x * 256 + threadIdx.x;
    if (idx >= NT1 * NT1) return;
    int ia = idx / NT1, id = idx % NT1;
    float a = -1.f + (float)ia * (2.f / NT);
    float d = -1.f + (float)id * (2.f / NT);
    float fq = qb2[0], fk = kb2[0];
#pragma unroll
    for (int m = 0; m < 16; ++m) {
        float hq = fmaf(a, qw1[m], fmaf(d, qw1[16 + m], qb1[m]));
        float hk = fmaf(a, kw1[m], fmaf(d, kw1[16 + m], kb1[m]));
        fq = fmaf(fsilu(hq), qw2[m], fq);
        fk = fmaf(fsilu(hk), kw2[m], fk);
    }
    T[idx] = packh2(fq, fk);
}

// ---------------- K1: vec_geom = vec @ W_geom (4 g-outputs per thread) ------
__global__ __launch_bounds__(256) void k_vecgeom(const float* __restrict__ vec,
                                                 const float* __restrict__ Wg,
                                                 float* __restrict__ vg) {
    __shared__ float Wl[NH * NG];
    for (int t = threadIdx.x; t < NH * NG; t += 256) Wl[t] = Wg[t];
    __syncthreads();

    int idx = blockIdx.x * 256 + threadIdx.x;   // 0 .. B*N*3*4 (exact grid)
    int gq = idx & 3;
    int rc = idx >> 2;                          // row = node*3+c
    const float4* vrow = reinterpret_cast<const float4*>(vec + rc * NH);
    float a0 = 0.f, a1 = 0.f, a2 = 0.f, a3 = 0.f;
#pragma unroll 8
    for (int h4 = 0; h4 < 32; ++h4) {
        float4 v = vrow[h4];
        int h = h4 * 4;
        float4 w0 = *reinterpret_cast<const float4*>(&Wl[(h + 0) * NG + gq * 4]);
        float4 w1 = *reinterpret_cast<const float4*>(&Wl[(h + 1) * NG + gq * 4]);
        float4 w2 = *reinterpret_cast<const float4*>(&Wl[(h + 2) * NG + gq * 4]);
        float4 w3 = *reinterpret_cast<const float4*>(&Wl[(h + 3) * NG + gq * 4]);
        a0 = fmaf(v.x, w0.x, a0); a1 = fmaf(v.x, w0.y, a1); a2 = fmaf(v.x, w0.z, a2); a3 = fmaf(v.x, w0.w, a3);
        a0 = fmaf(v.y, w1.x, a0); a1 = fmaf(v.y, w1.y, a1); a2 = fmaf(v.y, w1.z, a2); a3 = fmaf(v.y, w1.w, a3);
        a0 = fmaf(v.z, w2.x, a0); a1 = fmaf(v.z, w2.y, a1); a2 = fmaf(v.z, w2.z, a2); a3 = fmaf(v.z, w2.w, a3);
        a0 = fmaf(v.w, w3.x, a0); a1 = fmaf(v.w, w3.y, a1); a2 = fmaf(v.w, w3.z, a2); a3 = fmaf(v.w, w3.w, a3);
    }
    *reinterpret_cast<float4*>(vg + rc * NG + gq * 4) = make_float4(a0, a1, a2, a3);
}

// ---------------- K2: u[i] = sum_j normalize(vg[j]-vg[i]) -------------------
__global__ __launch_bounds__(256) void k_u(const float* __restrict__ vg,
                                           float* __restrict__ u) {
    int idx = blockIdx.x * 256 + threadIdx.x;
    int g = idx & 15;
    int bn = idx >> 4;
    int n = bn & (NN - 1);
    int base_i = bn * 48 + g;
    float vi0 = vg[base_i], vi1 = vg[base_i + 16], vi2 = vg[base_i + 32];
    float a0 = 0.f, a1 = 0.f, a2 = 0.f;
#pragma unroll
    for (int e = 0; e < 6; ++e) {
        int off = (e < 3) ? (e - 3) : (e - 2);
        int j = n + off;
        if (j < 0 || j >= NN) continue;
        int base_j = base_i + off * 48;
        float d0 = vg[base_j] - vi0;
        float d1 = vg[base_j + 16] - vi1;
        float d2 = vg[base_j + 32] - vi2;
        float r = frsq(fmaxf(d0 * d0 + d1 * d1 + d2 * d2, 1e-16f));
        a0 = fmaf(d0, r, a0); a1 = fmaf(d1, r, a1); a2 = fmaf(d2, r, a2);
    }
    u[base_i] = a0; u[base_i + 16] = a1; u[base_i + 32] = a2;
}

// ---------------- shared geometry+table device function ---------------------
__device__ __forceinline__ void edge_gates(
    int base_i, int base_j,
    float vi0, float vi1, float vi2,
    float ui0, float ui1, float ui2, float rnui,
    const float* __restrict__ vg, const float* __restrict__ u,
    const unsigned (&Ts)[NT1 * NT1], float& fq, float& fk) {
    float d0 = vg[base_j] - vi0;
    float d1 = vg[base_j + 16] - vi1;
    float d2 = vg[base_j + 32] - vi2;
    float rb = frsq(fmaxf(d0 * d0 + d1 * d1 + d2 * d2, 1e-16f));
    float e0 = d0 * rb, e1 = d1 * rb, e2 = d2 * rb;
    float uj0 = u[base_j], uj1 = u[base_j + 16], uj2 = u[base_j + 32];
    float die = ui0 * e0 + ui1 * e1 + ui2 * e2;
    float ang = fclamp1(die * rnui);
    float p0 = ui0 - die * e0, p1 = ui1 - die * e1, p2 = ui2 - die * e2;
    float dje = uj0 * e0 + uj1 * e1 + uj2 * e2;
    float q0 = uj0 - dje * e0, q1 = uj1 - dje * e1, q2 = uj2 - dje * e2;
    float dp = p0 * q0 + p1 * q1 + p2 * q2;
    float pp = fmaxf(p0 * p0 + p1 * p1 + p2 * p2, 1e-16f);
    float qq = fmaxf(q0 * q0 + q1 * q1 + q2 * q2, 1e-16f);
    float dih = fclamp1(dp * frsq(pp * qq));

    float af = fmaf(ang, (float)NT * 0.5f, (float)NT * 0.5f);
    float df_ = fmaf(dih, (float)NT * 0.5f, (float)NT * 0.5f);
    int ia = min((int)af, NT - 1);
    int id = min((int)df_, NT - 1);
    float fa = af - (float)ia;
    float fd = df_ - (float)id;
    const unsigned* t0 = &Ts[ia * NT1 + id];
    unsigned c00 = t0[0], c01 = t0[1], c10 = t0[NT1], c11 = t0[NT1 + 1];
    float l0q = fmaf(fd, h2lo(c01) - h2lo(c00), h2lo(c00));
    float h0q = fmaf(fd, h2lo(c11) - h2lo(c10), h2lo(c10));
    fq = fmaf(fa, h0q - l0q, l0q);
    float l0k = fmaf(fd, h2hi(c01) - h2hi(c00), h2hi(c00));
    float h0k = fmaf(fd, h2hi(c11) - h2hi(c10), h2hi(c10));
    fk = fmaf(fa, h0k - l0k, l0k);
}

// =================== SPLIT PATH ==============================================
// K3a: gates -> GT[grp][qk][e][16 rows][16 g] bf16, A-fragment tile order.
// One wave handles HALF a group (8 nodes x 6 edges); 8192 waves.
template <bool INT>
__device__ __forceinline__ void gates_half(
    int grp, int bn0, int n0, int sub, int lane,
    const float* __restrict__ vg, const float* __restrict__ u,
    const unsigned (&Ts)[NT1 * NT1], unsigned short* __restrict__ GT) {
    int nl = lane >> 4, g = lane & 15;
    size_t gbase = ((size_t)grp * 12) * 256;   // qk=0 slab; qk=1 at +6*256
#pragma unroll
    for (int i = 0; i < 2; ++i) {
        int nq = sub * 2 + i;
        int node = nq * 4 + nl;
        int bn = bn0 + node;
        int base_i = bn * 48 + g;
        float vi0 = vg[base_i], vi1 = vg[base_i + 16], vi2 = vg[base_i + 32];
        float ui0 = u[base_i],  ui1 = u[base_i + 16],  ui2 = u[base_i + 32];
        float rnui = frsq(fmaxf(ui0 * ui0 + ui1 * ui1 + ui2 * ui2, 1e-16f));
#pragma unroll
        for (int e = 0; e < 6; ++e) {
            int off = (e < 3) ? (e - 3) : (e - 2);
            bool valid = INT || ((unsigned)(n0 + node + off) < (unsigned)NN);
            float fq = 0.f, fk = 0.f;
            if (valid)
                edge_gates(base_i, base_i + off * 48, vi0, vi1, vi2,
                           ui0, ui1, ui2, rnui, vg, u, Ts, fq, fk);
            size_t o = gbase + (size_t)e * 256 + nq * 64 + lane;
            GT[o] = f2bf(fq);
            GT[o + 6 * 256] = f2bf(fk);
        }
    }
}

__global__ __launch_bounds__(256, 8) void k_gates(
    const float* __restrict__ vg, const float* __restrict__ u,
    const unsigned* __restrict__ T, unsigned short* __restrict__ GT) {
    __shared__ unsigned Ts[NT1 * NT1];
    int tid = threadIdx.x;
    for (int t = tid; t < NT1 * NT1; t += 256) Ts[t] = T[t];
    __syncthreads();

    int w = tid >> 6, lane = tid & 63;
    int gw = blockIdx.x * 4 + w;          // 8192 waves (exact grid)
    int grp = gw >> 1, sub = gw & 1;
    int bn0 = grp * 16;
    int n0 = bn0 & (NN - 1);
    bool interior = (n0 != 0) && (n0 != NN - 16);
    if (interior) gates_half<true>(grp, bn0, n0, sub, lane, vg, u, Ts, GT);
    else          gates_half<false>(grp, bn0, n0, sub, lane, vg, u, Ts, GT);
}

// K3b: MFMA logits (bias via C-operand) + sigmoid + x gather. Wave = (grp,qk).
template <bool INT>
__device__ __forceinline__ void apply_group(
    int grp, int bn0, int n0, int qk, int lane,
    const unsigned short* __restrict__ GT, const float* __restrict__ xs,
    const s16x8 (&Wl)[2][8][32], const float (&bs)[2][NH],
    float* __restrict__ out) {
    int c = lane & 15, rg = lane >> 4;
    s16x8 afr[6];
    int aidx = (lane & 15) * 2 + (lane >> 4);
    const unsigned short* gt = GT + ((size_t)(grp * 2 + qk) * 6) * 256;
#pragma unroll
    for (int e = 0; e < 6; ++e)
        afr[e] = (lane < 32)
            ? reinterpret_cast<const s16x8*>(gt + e * 256)[aidx]
            : (s16x8)0;

#pragma unroll
    for (int ht = 0; ht < 8; ++ht) {
        float xr[10];
#pragma unroll
        for (int d = 0; d < 10; ++d) {
            if (INT) {
                xr[d] = xs[(size_t)(bn0 + rg * 4 + d - 3) * NH + ht * 16 + c];
            } else {
                int gidx = bn0 + rg * 4 + d - 3;
                gidx = min(max(gidx, 0), NB * NN - 1);
                xr[d] = xs[(size_t)gidx * NH + ht * 16 + c];
            }
        }
        s16x8 bfr = (lane < 32) ? Wl[qk][ht][lane] : (s16x8)0;
        float b = bs[qk][ht * 16 + c];
        f32x4 bias4 = {b, b, b, b};
        f32x4 acc = {0.f, 0.f, 0.f, 0.f};
#pragma unroll
        for (int e = 0; e < 6; ++e) {
            f32x4 cc = __builtin_amdgcn_mfma_f32_16x16x32_bf16(afr[e], bfr, bias4, 0, 0, 0);
            int off = (e < 3) ? (e - 3) : (e - 2);
#pragma unroll
            for (int r = 0; r < 4; ++r) {
                float pr = fsigmoid(cc[r]);
                if (!INT) {
                    int jn = n0 + rg * 4 + r + off;
                    pr = ((unsigned)jn < (unsigned)NN) ? pr : 0.f;
                }
                acc[r] = fmaf(pr, xr[r + off + 3], acc[r]);
            }
        }
        float* o = out + (size_t)(bn0 + rg * 4) * NH + ht * 16 + c;
#pragma unroll
        for (int r = 0; r < 4; ++r) o[r * NH] = acc[r];
    }
}

__global__ __launch_bounds__(256, 8) void k_apply(
    const unsigned short* __restrict__ GT, const float* __restrict__ xs,
    const float* __restrict__ Wq, const float* __restrict__ bq,
    const float* __restrict__ Wk, const float* __restrict__ bk,
    float* __restrict__ outq, float* __restrict__ outk) {
    __shared__ s16x8 Wl[2][8][32];
    __shared__ float bs[2][NH];
    int tid = threadIdx.x;
    for (int slot = tid; slot < 2 * 8 * 32; slot += 256) {
        int lane_in = slot & 31;
        int frag = slot >> 5;
        int fqk = frag >> 3, fht = frag & 7;
        const float* W = fqk ? Wk : Wq;
        int k0 = (lane_in >> 4) * 8, fcol = lane_in & 15;
        s16x8 v;
#pragma unroll
        for (int i = 0; i < 8; ++i)
            v[i] = (short)f2bf(W[(k0 + i) * NH + fht * 16 + fcol]);
        Wl[fqk][fht][lane_in] = v;
    }
    if (tid < NH) bs[0][tid] = bq[tid];
    else bs[1][tid - NH] = bk[tid - NH];
    __syncthreads();

    int w = tid >> 6, lane = tid & 63;
    int gw = blockIdx.x * 4 + w;          // 8192 waves (exact grid)
    int grp = gw >> 1, qk = gw & 1;
    int bn0 = grp * 16;
    int n0 = bn0 & (NN - 1);
    float* out = qk ? outk : outq;
    bool interior = (n0 != 0) && (n0 != NN - 16);
    if (interior) apply_group<true>(grp, bn0, n0, qk, lane, GT, xs, Wl, bs, out);
    else          apply_group<false>(grp, bn0, n0, qk, lane, GT, xs, Wl, bs, out);
}

// =================== FUSED FALLBACK (R8) =====================================
template <bool INT>
__device__ __forceinline__ void run_group(
    int bn0, int n0, int w, int lane,
    const float* __restrict__ vg, const float* __restrict__ u,
    const float* __restrict__ xs, const unsigned (&Ts)[NT1 * NT1],
    unsigned short (&As)[4][2][6][16][16], const s16x8 (&Wl)[2][8][32],
    const float (&bs)[2][NH],
    float* __restrict__ outq, float* __restrict__ outk) {

    int nl = lane >> 4, g = lane & 15;
#pragma unroll
    for (int nq = 0; nq < 4; ++nq) {
        int node = nq * 4 + nl;
        int bn = bn0 + node;
        int base_i = bn * 48 + g;
        float vi0 = vg[base_i], vi1 = vg[base_i + 16], vi2 = vg[base_i + 32];
        float ui0 = u[base_i],  ui1 = u[base_i + 16],  ui2 = u[base_i + 32];
        float rnui = frsq(fmaxf(ui0 * ui0 + ui1 * ui1 + ui2 * ui2, 1e-16f));
#pragma unroll
        for (int e = 0; e < 6; ++e) {
            int off = (e < 3) ? (e - 3) : (e - 2);
            bool valid = INT || ((unsigned)(n0 + node + off) < (unsigned)NN);
            float fq = 0.f, fk = 0.f;
            if (valid)
                edge_gates(base_i, base_i + off * 48, vi0, vi1, vi2,
                           ui0, ui1, ui2, rnui, vg, u, Ts, fq, fk);
            As[w][0][e][node][g] = f2bf(fq);
            As[w][1][e][node][g] = f2bf(fk);
        }
    }
    asm volatile("" ::: "memory");

    s16x8 afr[2][6];
    int aidx = (lane & 15) * 2 + (lane >> 4);
#pragma unroll
    for (int qk = 0; qk < 2; ++qk)
#pragma unroll
        for (int e = 0; e < 6; ++e)
            afr[qk][e] = (lane < 32)
                ? reinterpret_cast<const s16x8*>(&As[w][qk][e][0][0])[aidx]
                : (s16x8)0;

    int c = lane & 15;
    int rg = lane >> 4;
#pragma unroll
    for (int ht = 0; ht < 8; ++ht) {
        float xr[10];
#pragma unroll
        for (int d = 0; d < 10; ++d) {
            if (INT) {
                xr[d] = xs[(size_t)(bn0 + rg * 4 + d - 3) * NH + ht * 16 + c];
            } else {
                int gidx = bn0 + rg * 4 + d - 3;
                gidx = min(max(gidx, 0), NB * NN - 1);
                xr[d] = xs[(size_t)gidx * NH + ht * 16 + c];
            }
        }
#pragma unroll
        for (int qk = 0; qk < 2; ++qk) {
            s16x8 bfr = (lane < 32) ? Wl[qk][ht][lane] : (s16x8)0;
            float b = bs[qk][ht * 16 + c];
            f32x4 bias4 = {b, b, b, b};
            f32x4 acc = {0.f, 0.f, 0.f, 0.f};
#pragma unroll
            for (int e = 0; e < 6; ++e) {
                f32x4 cc = __builtin_amdgcn_mfma_f32_16x16x32_bf16(afr[qk][e], bfr, bias4, 0, 0, 0);
                int off = (e < 3) ? (e - 3) : (e - 2);
#pragma unroll
                for (int r = 0; r < 4; ++r) {
                    float pr = fsigmoid(cc[r]);
                    if (!INT) {
                        int jn = n0 + rg * 4 + r + off;
                        pr = ((unsigned)jn < (unsigned)NN) ? pr : 0.f;
                    }
                    acc[r] = fmaf(pr, xr[r + off + 3], acc[r]);
                }
            }
            float* o = (qk ? outk : outq) + (size_t)(bn0 + rg * 4) * NH + ht * 16 + c;
#pragma unroll
            for (int r = 0; r < 4; ++r) o[r * NH] = acc[r];
        }
    }
    asm volatile("" ::: "memory");
}

__global__ __launch_bounds__(256, 4) void k_main(
    const float* __restrict__ vg, const float* __restrict__ u,
    const float* __restrict__ xs, const unsigned* __restrict__ T,
    const float* __restrict__ Wq, const float* __restrict__ bq,
    const float* __restrict__ Wk, const float* __restrict__ bk,
    float* __restrict__ outq, float* __restrict__ outk) {
    __shared__ unsigned Ts[NT1 * NT1];
    __shared__ __align__(16) unsigned short As[4][2][6][16][16];
    __shared__ s16x8 Wl[2][8][32];
    __shared__ float bs[2][NH];

    int tid = threadIdx.x;
    for (int t = tid; t < NT1 * NT1; t += 256) Ts[t] = T[t];
    for (int slot = tid; slot < 2 * 8 * 32; slot += 256) {
        int lane_in = slot & 31;
        int frag = slot >> 5;
        int fqk = frag >> 3, fht = frag & 7;
        const float* W = fqk ? Wk : Wq;
        int k0 = (lane_in >> 4) * 8, fcol = lane_in & 15;
        s16x8 v;
#pragma unroll
        for (int i = 0; i < 8; ++i)
            v[i] = (short)f2bf(W[(k0 + i) * NH + fht * 16 + fcol]);
        Wl[fqk][fht][lane_in] = v;
    }
    if (tid < NH) bs[0][tid] = bq[tid];
    else bs[1][tid - NH] = bk[tid - NH];

    int w = tid >> 6, lane = tid & 63;
    __syncthreads();

    int grp = blockIdx.x * 4 + w;
    int bn0 = grp * 16;
    int n0 = bn0 & (NN - 1);
    bool interior = (n0 != 0) && (n0 != NN - 16);
    if (interior)
        run_group<true>(bn0, n0, w, lane, vg, u, xs, Ts, As, Wl, bs, outq, outk);
    else
        run_group<false>(bn0, n0, w, lane, vg, u, xs, Ts, As, Wl, bs, outq, outk);
}

extern "C" void kernel_launch(void* const* d_in, const int* in_sizes, int n_in,
                              void* d_out, int out_size, void* d_ws, size_t ws_size,
                              hipStream_t stream) {
    const float* xs   = (const float*)d_in[0];
    const float* vec  = (const float*)d_in[1];
    const float* Wg   = (const float*)d_in[2];
    const float* qw1  = (const float*)d_in[3];
    const float* qb1  = (const float*)d_in[4];
    const float* qw2  = (const float*)d_in[5];
    const float* qb2  = (const float*)d_in[6];
    const float* kw1  = (const float*)d_in[7];
    const float* kb1  = (const float*)d_in[8];
    const float* kw2  = (const float*)d_in[9];
    const float* kb2  = (const float*)d_in[10];
    const float* Wq   = (const float*)d_in[11];
    const float* bq   = (const float*)d_in[12];
    const float* Wk   = (const float*)d_in[13];
    const float* bk   = (const float*)d_in[14];

    size_t vg_f = (size_t)NB * NN * 48;                 // 3,145,728 floats
    float* vg = (float*)d_ws;
    float* u  = vg + vg_f;
    unsigned* T = (unsigned*)(u + vg_f);
    size_t t_off = 2 * vg_f * 4;                        // bytes
    size_t gt_off = t_off + 8192;                       // 16B-aligned
    unsigned short* GT = (unsigned short*)((char*)d_ws + gt_off);
    size_t need = gt_off + (size_t)NGRP * 12 * 256 * 2; // + 25.2 MB
    float* outq = (float*)d_out;
    float* outk = outq + (size_t)NB * NN * NH;

    k_table<<<dim3((NT1 * NT1 + 255) / 256), dim3(256), 0, stream>>>(
        qw1, qb1, qw2, qb2, kw1, kb1, kw2, kb2, T);
    k_vecgeom<<<dim3(3072), dim3(256), 0, stream>>>(vec, Wg, vg);
    k_u<<<dim3(4096), dim3(256), 0, stream>>>(vg, u);

    if (ws_size >= need) {
        k_gates<<<dim3(2048), dim3(256), 0, stream>>>(vg, u, T, GT);
        k_apply<<<dim3(2048), dim3(256), 0, stream>>>(
            GT, xs, Wq, bq, Wk, bk, outq, outk);
    } else {
        k_main<<<dim3(1024), dim3(256), 0, stream>>>(
            vg, u, xs, T, Wq, bq, Wk, bk, outq, outk);
    }
}

// Round 10
// 80.018 us; speedup vs baseline: 1.6190x; 1.6190x over previous
//
#include <hip/hip_runtime.h>

constexpr int NB = 8;
constexpr int NN = 8192;
constexpr int NH = 128;
constexpr int NG = 16;
constexpr int NT = 36;            // table intervals per axis
constexpr int NT1 = NT + 1;       // 37 grid points

typedef short s16x8 __attribute__((ext_vector_type(8)));
typedef float f32x4 __attribute__((ext_vector_type(4)));

__device__ __forceinline__ float frcp(float x) { return __builtin_amdgcn_rcpf(x); }
__device__ __forceinline__ float frsq(float x) { return __builtin_amdgcn_rsqf(x); }
__device__ __forceinline__ float fsigmoid(float x) { return frcp(1.f + __expf(-x)); }
__device__ __forceinline__ float fsilu(float x) { return x * fsigmoid(x); }
__device__ __forceinline__ float fclamp1(float x) { return fminf(fmaxf(x, -1.f), 1.f); }

__device__ __forceinline__ unsigned short f2bf(float x) {  // f32 -> bf16 RTNE
    unsigned u = __builtin_bit_cast(unsigned, x);
    return (unsigned short)((u + 0x7FFFu + ((u >> 16) & 1u)) >> 16);
}
__device__ __forceinline__ unsigned packh2(float a, float b) {
    unsigned short lo = __builtin_bit_cast(unsigned short, (__fp16)a);
    unsigned short hi = __builtin_bit_cast(unsigned short, (__fp16)b);
    return (unsigned)lo | ((unsigned)hi << 16);
}
__device__ __forceinline__ float h2lo(unsigned u) {
    return (float)__builtin_bit_cast(__fp16, (unsigned short)(u & 0xFFFFu));
}
__device__ __forceinline__ float h2hi(unsigned u) {
    return (float)__builtin_bit_cast(__fp16, (unsigned short)(u >> 16));
}

// ---------------- K0: build NT1 x NT1 bilinear table of both gate MLPs ------
__global__ __launch_bounds__(256) void k_table(
    const float* __restrict__ qw1, const float* __restrict__ qb1,
    const float* __restrict__ qw2, const float* __restrict__ qb2,
    const float* __restrict__ kw1, const float* __restrict__ kb1,
    const float* __restrict__ kw2, const float* __restrict__ kb2,
    unsigned* __restrict__ T) {
    int idx = blockIdx.x * 256 + threadIdx.x;
    if (idx >= NT1 * NT1) return;
    int ia = idx / NT1, id = idx % NT1;
    float a = -1.f + (float)ia * (2.f / NT);
    float d = -1.f + (float)id * (2.f / NT);
    float fq = qb2[0], fk = kb2[0];
#pragma unroll
    for (int m = 0; m < 16; ++m) {
        float hq = fmaf(a, qw1[m], fmaf(d, qw1[16 + m], qb1[m]));
        float hk = fmaf(a, kw1[m], fmaf(d, kw1[16 + m], kb1[m]));
        fq = fmaf(fsilu(hq), qw2[m], fq);
        fk = fmaf(fsilu(hk), kw2[m], fk);
    }
    T[idx] = packh2(fq, fk);
}

// ---------------- K1: vec_geom = vec @ W_geom (4 g-outputs per thread) ------
__global__ __launch_bounds__(256) void k_vecgeom(const float* __restrict__ vec,
                                                 const float* __restrict__ Wg,
                                                 float* __restrict__ vg) {
    __shared__ float Wl[NH * NG];
    for (int t = threadIdx.x; t < NH * NG; t += 256) Wl[t] = Wg[t];
    __syncthreads();

    int idx = blockIdx.x * 256 + threadIdx.x;   // 0 .. B*N*3*4 (exact grid)
    int gq = idx & 3;
    int rc = idx >> 2;                          // row = node*3+c
    const float4* vrow = reinterpret_cast<const float4*>(vec + rc * NH);
    float a0 = 0.f, a1 = 0.f, a2 = 0.f, a3 = 0.f;
#pragma unroll 8
    for (int h4 = 0; h4 < 32; ++h4) {
        float4 v = vrow[h4];
        int h = h4 * 4;
        float4 w0 = *reinterpret_cast<const float4*>(&Wl[(h + 0) * NG + gq * 4]);
        float4 w1 = *reinterpret_cast<const float4*>(&Wl[(h + 1) * NG + gq * 4]);
        float4 w2 = *reinterpret_cast<const float4*>(&Wl[(h + 2) * NG + gq * 4]);
        float4 w3 = *reinterpret_cast<const float4*>(&Wl[(h + 3) * NG + gq * 4]);
        a0 = fmaf(v.x, w0.x, a0); a1 = fmaf(v.x, w0.y, a1); a2 = fmaf(v.x, w0.z, a2); a3 = fmaf(v.x, w0.w, a3);
        a0 = fmaf(v.y, w1.x, a0); a1 = fmaf(v.y, w1.y, a1); a2 = fmaf(v.y, w1.z, a2); a3 = fmaf(v.y, w1.w, a3);
        a0 = fmaf(v.z, w2.x, a0); a1 = fmaf(v.z, w2.y, a1); a2 = fmaf(v.z, w2.z, a2); a3 = fmaf(v.z, w2.w, a3);
        a0 = fmaf(v.w, w3.x, a0); a1 = fmaf(v.w, w3.y, a1); a2 = fmaf(v.w, w3.z, a2); a3 = fmaf(v.w, w3.w, a3);
    }
    *reinterpret_cast<float4*>(vg + rc * NG + gq * 4) = make_float4(a0, a1, a2, a3);
}

// ---------------- K2: u[i] = sum_j normalize(vg[j]-vg[i]) -------------------
__global__ __launch_bounds__(256) void k_u(const float* __restrict__ vg,
                                           float* __restrict__ u) {
    int idx = blockIdx.x * 256 + threadIdx.x;
    int g = idx & 15;
    int bn = idx >> 4;
    int n = bn & (NN - 1);
    int base_i = bn * 48 + g;
    float vi0 = vg[base_i], vi1 = vg[base_i + 16], vi2 = vg[base_i + 32];
    float a0 = 0.f, a1 = 0.f, a2 = 0.f;
#pragma unroll
    for (int e = 0; e < 6; ++e) {
        int off = (e < 3) ? (e - 3) : (e - 2);
        int j = n + off;
        if (j < 0 || j >= NN) continue;
        int base_j = base_i + off * 48;
        float d0 = vg[base_j] - vi0;
        float d1 = vg[base_j + 16] - vi1;
        float d2 = vg[base_j + 32] - vi2;
        float r = frsq(fmaxf(d0 * d0 + d1 * d1 + d2 * d2, 1e-16f));
        a0 = fmaf(d0, r, a0); a1 = fmaf(d1, r, a1); a2 = fmaf(d2, r, a2);
    }
    u[base_i] = a0; u[base_i + 16] = a1; u[base_i + 32] = a2;
}

// ---------------- shared geometry+table device function ---------------------
__device__ __forceinline__ void edge_gates(
    int base_i, int base_j,
    float vi0, float vi1, float vi2,
    float ui0, float ui1, float ui2, float rnui,
    const float* __restrict__ vg, const float* __restrict__ u,
    const unsigned (&Ts)[NT1 * NT1], float& fq, float& fk) {
    float d0 = vg[base_j] - vi0;
    float d1 = vg[base_j + 16] - vi1;
    float d2 = vg[base_j + 32] - vi2;
    float rb = frsq(fmaxf(d0 * d0 + d1 * d1 + d2 * d2, 1e-16f));
    float e0 = d0 * rb, e1 = d1 * rb, e2 = d2 * rb;
    float uj0 = u[base_j], uj1 = u[base_j + 16], uj2 = u[base_j + 32];
    float die = ui0 * e0 + ui1 * e1 + ui2 * e2;
    float ang = fclamp1(die * rnui);
    float p0 = ui0 - die * e0, p1 = ui1 - die * e1, p2 = ui2 - die * e2;
    float dje = uj0 * e0 + uj1 * e1 + uj2 * e2;
    float q0 = uj0 - dje * e0, q1 = uj1 - dje * e1, q2 = uj2 - dje * e2;
    float dp = p0 * q0 + p1 * q1 + p2 * q2;
    float pp = fmaxf(p0 * p0 + p1 * p1 + p2 * p2, 1e-16f);
    float qq = fmaxf(q0 * q0 + q1 * q1 + q2 * q2, 1e-16f);
    float dih = fclamp1(dp * frsq(pp * qq));

    float af = fmaf(ang, (float)NT * 0.5f, (float)NT * 0.5f);
    float df_ = fmaf(dih, (float)NT * 0.5f, (float)NT * 0.5f);
    int ia = min((int)af, NT - 1);
    int id = min((int)df_, NT - 1);
    float fa = af - (float)ia;
    float fd = df_ - (float)id;
    const unsigned* t0 = &Ts[ia * NT1 + id];
    unsigned c00 = t0[0], c01 = t0[1], c10 = t0[NT1], c11 = t0[NT1 + 1];
    float l0q = fmaf(fd, h2lo(c01) - h2lo(c00), h2lo(c00));
    float h0q = fmaf(fd, h2lo(c11) - h2lo(c10), h2lo(c10));
    fq = fmaf(fa, h0q - l0q, l0q);
    float l0k = fmaf(fd, h2hi(c01) - h2hi(c00), h2hi(c00));
    float h0k = fmaf(fd, h2hi(c11) - h2hi(c10), h2hi(c10));
    fk = fmaf(fa, h0k - l0k, l0k);
}

// ---------------- K3 Phase A: half a group's gates per wave -----------------
template <bool INT>
__device__ __forceinline__ void phaseA(
    int bn0, int n0, int gh, int sub, int lane,
    const float* __restrict__ vg, const float* __restrict__ u,
    const unsigned (&Ts)[NT1 * NT1],
    unsigned short (&As)[2][2][6][16][16]) {
    int nl = lane >> 4, g = lane & 15;
#pragma unroll
    for (int i = 0; i < 2; ++i) {
        int nq = sub * 2 + i;
        int node = nq * 4 + nl;
        int bn = bn0 + node;
        int base_i = bn * 48 + g;
        float vi0 = vg[base_i], vi1 = vg[base_i + 16], vi2 = vg[base_i + 32];
        float ui0 = u[base_i],  ui1 = u[base_i + 16],  ui2 = u[base_i + 32];
        float rnui = frsq(fmaxf(ui0 * ui0 + ui1 * ui1 + ui2 * ui2, 1e-16f));
#pragma unroll
        for (int e = 0; e < 6; ++e) {
            int off = (e < 3) ? (e - 3) : (e - 2);
            bool valid = INT || ((unsigned)(n0 + node + off) < (unsigned)NN);
            float fq = 0.f, fk = 0.f;
            if (valid)
                edge_gates(base_i, base_i + off * 48, vi0, vi1, vi2,
                           ui0, ui1, ui2, rnui, vg, u, Ts, fq, fk);
            As[gh][0][e][node][g] = f2bf(fq);
            As[gh][1][e][node][g] = f2bf(fk);
        }
    }
}

// ---------------- K3 Phase B: one qk of one group per wave ------------------
template <bool INT>
__device__ __forceinline__ void phaseB(
    int bn0, int n0, int gh, int qk, int lane,
    const float* __restrict__ xs,
    const unsigned short (&As)[2][2][6][16][16],
    const s16x8 (&Wl)[2][8][32], const float (&bs)[2][NH],
    float* __restrict__ out) {
    int c = lane & 15, rg = lane >> 4;
    s16x8 afr[6];
    int aidx = c * 2 + rg;   // valid for lane<32: node=c, g-half=rg
#pragma unroll
    for (int e = 0; e < 6; ++e)
        afr[e] = (lane < 32)
            ? reinterpret_cast<const s16x8*>(&As[gh][qk][e][0][0])[aidx]
            : (s16x8)0;

#pragma unroll
    for (int ht = 0; ht < 8; ++ht) {
        float xr[10];
#pragma unroll
        for (int d = 0; d < 10; ++d) {
            if (INT) {
                xr[d] = xs[(size_t)(bn0 + rg * 4 + d - 3) * NH + ht * 16 + c];
            } else {
                int gidx = bn0 + rg * 4 + d - 3;
                gidx = min(max(gidx, 0), NB * NN - 1);
                xr[d] = xs[(size_t)gidx * NH + ht * 16 + c];
            }
        }
        s16x8 bfr = (lane < 32) ? Wl[qk][ht][lane] : (s16x8)0;
        float b = bs[qk][ht * 16 + c];
        f32x4 bias4 = {b, b, b, b};
        f32x4 acc = {0.f, 0.f, 0.f, 0.f};
#pragma unroll
        for (int e = 0; e < 6; ++e) {
            f32x4 cc = __builtin_amdgcn_mfma_f32_16x16x32_bf16(afr[e], bfr, bias4, 0, 0, 0);
            int off = (e < 3) ? (e - 3) : (e - 2);
#pragma unroll
            for (int r = 0; r < 4; ++r) {
                float pr = fsigmoid(cc[r]);
                if (!INT) {
                    int jn = n0 + rg * 4 + r + off;
                    pr = ((unsigned)jn < (unsigned)NN) ? pr : 0.f;
                }
                acc[r] = fmaf(pr, xr[r + off + 3], acc[r]);
            }
        }
        float* o = out + (size_t)(bn0 + rg * 4) * NH + ht * 16 + c;
#pragma unroll
        for (int r = 0; r < 4; ++r) o[r * NH] = acc[r];
    }
}

// ---------------- K3: fused, 2 groups/block, qk-split Phase B ---------------
__global__ __launch_bounds__(256, 5) void k_main(
    const float* __restrict__ vg, const float* __restrict__ u,
    const float* __restrict__ xs, const unsigned* __restrict__ T,
    const float* __restrict__ Wq, const float* __restrict__ bq,
    const float* __restrict__ Wk, const float* __restrict__ bk,
    float* __restrict__ outq, float* __restrict__ outk) {
    __shared__ unsigned Ts[NT1 * NT1];                            // 5.5 KB
    __shared__ __align__(16) unsigned short As[2][2][6][16][16];  // 12 KB
    __shared__ s16x8 Wl[2][8][32];                                // 8 KB
    __shared__ float bs[2][NH];                                   // 1 KB

    int tid = threadIdx.x;
    for (int t = tid; t < NT1 * NT1; t += 256) Ts[t] = T[t];

    // B-fragments, col mapping global_col = ht*16 + c; k rows = g (0..15)
    for (int slot = tid; slot < 2 * 8 * 32; slot += 256) {
        int lane_in = slot & 31;
        int frag = slot >> 5;
        int fqk = frag >> 3, fht = frag & 7;
        const float* W = fqk ? Wk : Wq;
        int k0 = (lane_in >> 4) * 8, fcol = lane_in & 15;
        s16x8 v;
#pragma unroll
        for (int i = 0; i < 8; ++i)
            v[i] = (short)f2bf(W[(k0 + i) * NH + fht * 16 + fcol]);
        Wl[fqk][fht][lane_in] = v;
    }
    if (tid < NH) bs[0][tid] = bq[tid];
    else bs[1][tid - NH] = bk[tid - NH];

    int w = tid >> 6, lane = tid & 63;
    int gh = w >> 1, sub = w & 1;
    int grp = blockIdx.x * 2 + gh;     // 2048 blocks x 2 groups (exact)
    int bn0 = grp * 16;
    int n0 = bn0 & (NN - 1);
    bool interior = (n0 != 0) && (n0 != NN - 16);

    __syncthreads();   // Ts/Wl/bs ready

    if (interior) phaseA<true>(bn0, n0, gh, sub, lane, vg, u, Ts, As);
    else          phaseA<false>(bn0, n0, gh, sub, lane, vg, u, Ts, As);

    __syncthreads();   // As ready (produced by both waves of this group)

    float* out = sub ? outk : outq;
    if (interior) phaseB<true>(bn0, n0, gh, sub, lane, xs, As, Wl, bs, out);
    else          phaseB<false>(bn0, n0, gh, sub, lane, xs, As, Wl, bs, out);
}

extern "C" void kernel_launch(void* const* d_in, const int* in_sizes, int n_in,
                              void* d_out, int out_size, void* d_ws, size_t ws_size,
                              hipStream_t stream) {
    const float* xs   = (const float*)d_in[0];
    const float* vec  = (const float*)d_in[1];
    const float* Wg   = (const float*)d_in[2];
    const float* qw1  = (const float*)d_in[3];
    const float* qb1  = (const float*)d_in[4];
    const float* qw2  = (const float*)d_in[5];
    const float* qb2  = (const float*)d_in[6];
    const float* kw1  = (const float*)d_in[7];
    const float* kb1  = (const float*)d_in[8];
    const float* kw2  = (const float*)d_in[9];
    const float* kb2  = (const float*)d_in[10];
    const float* Wq   = (const float*)d_in[11];
    const float* bq   = (const float*)d_in[12];
    const float* Wk   = (const float*)d_in[13];
    const float* bk   = (const float*)d_in[14];

    size_t vg_f = (size_t)NB * NN * 48;
    float* vg = (float*)d_ws;
    float* u  = vg + vg_f;
    unsigned* T = (unsigned*)(u + vg_f);
    float* outq = (float*)d_out;
    float* outk = outq + (size_t)NB * NN * NH;

    k_table<<<dim3((NT1 * NT1 + 255) / 256), dim3(256), 0, stream>>>(
        qw1, qb1, qw2, qb2, kw1, kb1, kw2, kb2, T);
    k_vecgeom<<<dim3(3072), dim3(256), 0, stream>>>(vec, Wg, vg);
    k_u<<<dim3(4096), dim3(256), 0, stream>>>(vg, u);
    k_main<<<dim3(2048), dim3(256), 0, stream>>>(
        vg, u, xs, T, Wq, bq, Wk, bk, outq, outk);
}

// Round 11
// 79.737 us; speedup vs baseline: 1.6247x; 1.0035x over previous
//
#include <hip/hip_runtime.h>

constexpr int NB = 8;
constexpr int NN = 8192;
constexpr int NH = 128;
constexpr int NG = 16;
constexpr int NT = 36;            // table intervals per axis
constexpr int NT1 = NT + 1;       // 37 grid points
constexpr float NLOG2E = -1.44269504088896f;

typedef short s16x8 __attribute__((ext_vector_type(8)));
typedef float f32x4 __attribute__((ext_vector_type(4)));

__device__ __forceinline__ float frcp(float x) { return __builtin_amdgcn_rcpf(x); }
__device__ __forceinline__ float frsq(float x) { return __builtin_amdgcn_rsqf(x); }
__device__ __forceinline__ float fexp2(float x) {
#if __has_builtin(__builtin_amdgcn_exp2f)
    return __builtin_amdgcn_exp2f(x);
#else
    return __expf(x * 0.69314718056f);
#endif
}
__device__ __forceinline__ float fsigmoid(float x) { return frcp(1.f + __expf(-x)); }
__device__ __forceinline__ float fsilu(float x) { return x * fsigmoid(x); }
__device__ __forceinline__ float fclamp1(float x) { return fminf(fmaxf(x, -1.f), 1.f); }

__device__ __forceinline__ unsigned short f2bf(float x) {  // f32 -> bf16 RTNE
    unsigned u = __builtin_bit_cast(unsigned, x);
    return (unsigned short)((u + 0x7FFFu + ((u >> 16) & 1u)) >> 16);
}
__device__ __forceinline__ unsigned packh2(float a, float b) {
    unsigned short lo = __builtin_bit_cast(unsigned short, (__fp16)a);
    unsigned short hi = __builtin_bit_cast(unsigned short, (__fp16)b);
    return (unsigned)lo | ((unsigned)hi << 16);
}
__device__ __forceinline__ float h2lo(unsigned u) {
    return (float)__builtin_bit_cast(__fp16, (unsigned short)(u & 0xFFFFu));
}
__device__ __forceinline__ float h2hi(unsigned u) {
    return (float)__builtin_bit_cast(__fp16, (unsigned short)(u >> 16));
}

// ---------------- K0: build NT1 x NT1 bilinear table of both gate MLPs ------
__global__ __launch_bounds__(256) void k_table(
    const float* __restrict__ qw1, const float* __restrict__ qb1,
    const float* __restrict__ qw2, const float* __restrict__ qb2,
    const float* __restrict__ kw1, const float* __restrict__ kb1,
    const float* __restrict__ kw2, const float* __restrict__ kb2,
    unsigned* __restrict__ T) {
    int idx = blockIdx.x * 256 + threadIdx.x;
    if (idx >= NT1 * NT1) return;
    int ia = idx / NT1, id = idx % NT1;
    float a = -1.f + (float)ia * (2.f / NT);
    float d = -1.f + (float)id * (2.f / NT);
    float fq = qb2[0], fk = kb2[0];
#pragma unroll
    for (int m = 0; m < 16; ++m) {
        float hq = fmaf(a, qw1[m], fmaf(d, qw1[16 + m], qb1[m]));
        float hk = fmaf(a, kw1[m], fmaf(d, kw1[16 + m], kb1[m]));
        fq = fmaf(fsilu(hq), qw2[m], fq);
        fk = fmaf(fsilu(hk), kw2[m], fk);
    }
    T[idx] = packh2(fq, fk);
}

// ---------------- K1: vec_geom = vec @ W_geom (4 g-outputs per thread) ------
__global__ __launch_bounds__(256) void k_vecgeom(const float* __restrict__ vec,
                                                 const float* __restrict__ Wg,
                                                 float* __restrict__ vg) {
    __shared__ float Wl[NH * NG];
    for (int t = threadIdx.x; t < NH * NG; t += 256) Wl[t] = Wg[t];
    __syncthreads();

    int idx = blockIdx.x * 256 + threadIdx.x;   // 0 .. B*N*3*4 (exact grid)
    int gq = idx & 3;
    int rc = idx >> 2;                          // row = node*3+c
    const float4* vrow = reinterpret_cast<const float4*>(vec + rc * NH);
    float a0 = 0.f, a1 = 0.f, a2 = 0.f, a3 = 0.f;
#pragma unroll 8
    for (int h4 = 0; h4 < 32; ++h4) {
        float4 v = vrow[h4];
        int h = h4 * 4;
        float4 w0 = *reinterpret_cast<const float4*>(&Wl[(h + 0) * NG + gq * 4]);
        float4 w1 = *reinterpret_cast<const float4*>(&Wl[(h + 1) * NG + gq * 4]);
        float4 w2 = *reinterpret_cast<const float4*>(&Wl[(h + 2) * NG + gq * 4]);
        float4 w3 = *reinterpret_cast<const float4*>(&Wl[(h + 3) * NG + gq * 4]);
        a0 = fmaf(v.x, w0.x, a0); a1 = fmaf(v.x, w0.y, a1); a2 = fmaf(v.x, w0.z, a2); a3 = fmaf(v.x, w0.w, a3);
        a0 = fmaf(v.y, w1.x, a0); a1 = fmaf(v.y, w1.y, a1); a2 = fmaf(v.y, w1.z, a2); a3 = fmaf(v.y, w1.w, a3);
        a0 = fmaf(v.z, w2.x, a0); a1 = fmaf(v.z, w2.y, a1); a2 = fmaf(v.z, w2.z, a2); a3 = fmaf(v.z, w2.w, a3);
        a0 = fmaf(v.w, w3.x, a0); a1 = fmaf(v.w, w3.y, a1); a2 = fmaf(v.w, w3.z, a2); a3 = fmaf(v.w, w3.w, a3);
    }
    *reinterpret_cast<float4*>(vg + rc * NG + gq * 4) = make_float4(a0, a1, a2, a3);
}

// ---------------- K2: u[i] = sum_j normalize(vg[j]-vg[i]) -------------------
__global__ __launch_bounds__(256) void k_u(const float* __restrict__ vg,
                                           float* __restrict__ u) {
    int idx = blockIdx.x * 256 + threadIdx.x;
    int g = idx & 15;
    int bn = idx >> 4;
    int n = bn & (NN - 1);
    int base_i = bn * 48 + g;
    float vi0 = vg[base_i], vi1 = vg[base_i + 16], vi2 = vg[base_i + 32];
    float a0 = 0.f, a1 = 0.f, a2 = 0.f;
#pragma unroll
    for (int e = 0; e < 6; ++e) {
        int off = (e < 3) ? (e - 3) : (e - 2);
        int j = n + off;
        if (j < 0 || j >= NN) continue;
        int base_j = base_i + off * 48;
        float d0 = vg[base_j] - vi0;
        float d1 = vg[base_j + 16] - vi1;
        float d2 = vg[base_j + 32] - vi2;
        float r = frsq(fmaxf(d0 * d0 + d1 * d1 + d2 * d2, 1e-16f));
        a0 = fmaf(d0, r, a0); a1 = fmaf(d1, r, a1); a2 = fmaf(d2, r, a2);
    }
    u[base_i] = a0; u[base_i + 16] = a1; u[base_i + 32] = a2;
}

// ---------------- shared geometry+table device function ---------------------
__device__ __forceinline__ void edge_gates(
    int base_i, int base_j,
    float vi0, float vi1, float vi2,
    float ui0, float ui1, float ui2, float rnui,
    const float* __restrict__ vg, const float* __restrict__ u,
    const unsigned (&Ts)[NT1 * NT1], float& fq, float& fk) {
    float d0 = vg[base_j] - vi0;
    float d1 = vg[base_j + 16] - vi1;
    float d2 = vg[base_j + 32] - vi2;
    float rb = frsq(fmaxf(d0 * d0 + d1 * d1 + d2 * d2, 1e-16f));
    float e0 = d0 * rb, e1 = d1 * rb, e2 = d2 * rb;
    float uj0 = u[base_j], uj1 = u[base_j + 16], uj2 = u[base_j + 32];
    float die = ui0 * e0 + ui1 * e1 + ui2 * e2;
    float ang = fclamp1(die * rnui);
    float p0 = ui0 - die * e0, p1 = ui1 - die * e1, p2 = ui2 - die * e2;
    float dje = uj0 * e0 + uj1 * e1 + uj2 * e2;
    float q0 = uj0 - dje * e0, q1 = uj1 - dje * e1, q2 = uj2 - dje * e2;
    float dp = p0 * q0 + p1 * q1 + p2 * q2;
    float pp = fmaxf(p0 * p0 + p1 * p1 + p2 * p2, 1e-16f);
    float qq = fmaxf(q0 * q0 + q1 * q1 + q2 * q2, 1e-16f);
    float dih = fclamp1(dp * frsq(pp * qq));

    float af = fmaf(ang, (float)NT * 0.5f, (float)NT * 0.5f);
    float df_ = fmaf(dih, (float)NT * 0.5f, (float)NT * 0.5f);
    int ia = min((int)af, NT - 1);
    int id = min((int)df_, NT - 1);
    float fa = af - (float)ia;
    float fd = df_ - (float)id;
    const unsigned* t0 = &Ts[ia * NT1 + id];
    unsigned c00 = t0[0], c01 = t0[1], c10 = t0[NT1], c11 = t0[NT1 + 1];
    float l0q = fmaf(fd, h2lo(c01) - h2lo(c00), h2lo(c00));
    float h0q = fmaf(fd, h2lo(c11) - h2lo(c10), h2lo(c10));
    fq = fmaf(fa, h0q - l0q, l0q);
    float l0k = fmaf(fd, h2hi(c01) - h2hi(c00), h2hi(c00));
    float h0k = fmaf(fd, h2hi(c11) - h2hi(c10), h2hi(c10));
    fk = fmaf(fa, h0k - l0k, l0k);
}

// ---------------- K3 Phase A: half a group's gates per wave -----------------
template <bool INT>
__device__ __forceinline__ void phaseA(
    int bn0, int n0, int gh, int sub, int lane,
    const float* __restrict__ vg, const float* __restrict__ u,
    const unsigned (&Ts)[NT1 * NT1],
    unsigned short (&As)[2][2][6][16][16]) {
    int nl = lane >> 4, g = lane & 15;
#pragma unroll
    for (int i = 0; i < 2; ++i) {
        int nq = sub * 2 + i;
        int node = nq * 4 + nl;
        int bn = bn0 + node;
        int base_i = bn * 48 + g;
        float vi0 = vg[base_i], vi1 = vg[base_i + 16], vi2 = vg[base_i + 32];
        float ui0 = u[base_i],  ui1 = u[base_i + 16],  ui2 = u[base_i + 32];
        float rnui = frsq(fmaxf(ui0 * ui0 + ui1 * ui1 + ui2 * ui2, 1e-16f));
#pragma unroll
        for (int e = 0; e < 6; ++e) {
            int off = (e < 3) ? (e - 3) : (e - 2);
            bool valid = INT || ((unsigned)(n0 + node + off) < (unsigned)NN);
            float fq = 0.f, fk = 0.f;
            if (valid)
                edge_gates(base_i, base_i + off * 48, vi0, vi1, vi2,
                           ui0, ui1, ui2, rnui, vg, u, Ts, fq, fk);
            As[gh][0][e][node][g] = f2bf(fq);
            As[gh][1][e][node][g] = f2bf(fk);
        }
    }
}

// ---------------- K3 Phase B: one qk of one group per wave ------------------
// Wl/bs hold -log2(e) * (W, b): MFMA emits z = -logit*log2e; sig = rcp(1+2^z).
template <bool INT>
__device__ __forceinline__ void phaseB(
    int bn0, int n0, int gh, int qk, int lane,
    const float* __restrict__ xs,
    const unsigned short (&As)[2][2][6][16][16],
    const s16x8 (&Wl)[2][8][32], const float (&bs)[2][NH],
    float* __restrict__ out) {
    int c = lane & 15, rg = lane >> 4;
    s16x8 afr[6];
    int aidx = c * 2 + rg;   // valid for lane<32: node=c, g-half=rg
#pragma unroll
    for (int e = 0; e < 6; ++e)
        afr[e] = (lane < 32)
            ? reinterpret_cast<const s16x8*>(&As[gh][qk][e][0][0])[aidx]
            : (s16x8)0;

#pragma unroll
    for (int ht = 0; ht < 8; ++ht) {
        float xr[10];
#pragma unroll
        for (int d = 0; d < 10; ++d) {
            if (INT) {
                xr[d] = xs[(size_t)(bn0 + rg * 4 + d - 3) * NH + ht * 16 + c];
            } else {
                int gidx = bn0 + rg * 4 + d - 3;
                gidx = min(max(gidx, 0), NB * NN - 1);
                xr[d] = xs[(size_t)gidx * NH + ht * 16 + c];
            }
        }
        s16x8 bfr = (lane < 32) ? Wl[qk][ht][lane] : (s16x8)0;
        float b = bs[qk][ht * 16 + c];
        f32x4 bias4 = {b, b, b, b};
        f32x4 acc = {0.f, 0.f, 0.f, 0.f};
#pragma unroll
        for (int e = 0; e < 6; ++e) {
            f32x4 cc = __builtin_amdgcn_mfma_f32_16x16x32_bf16(afr[e], bfr, bias4, 0, 0, 0);
            int off = (e < 3) ? (e - 3) : (e - 2);
#pragma unroll
            for (int r = 0; r < 4; ++r) {
                float pr = frcp(1.f + fexp2(cc[r]));   // sigmoid(logit)
                if (!INT) {
                    int jn = n0 + rg * 4 + r + off;
                    pr = ((unsigned)jn < (unsigned)NN) ? pr : 0.f;
                }
                acc[r] = fmaf(pr, xr[r + off + 3], acc[r]);
            }
        }
        float* o = out + (size_t)(bn0 + rg * 4) * NH + ht * 16 + c;
#pragma unroll
        for (int r = 0; r < 4; ++r) o[r * NH] = acc[r];
    }
}

// ---------------- K3: fused, 2 groups/block x 2 iterations (single round) ---
__global__ __launch_bounds__(256, 4) void k_main(
    const float* __restrict__ vg, const float* __restrict__ u,
    const float* __restrict__ xs, const unsigned* __restrict__ T,
    const float* __restrict__ Wq, const float* __restrict__ bq,
    const float* __restrict__ Wk, const float* __restrict__ bk,
    float* __restrict__ outq, float* __restrict__ outk) {
    __shared__ unsigned Ts[NT1 * NT1];                            // 5.5 KB
    __shared__ __align__(16) unsigned short As[2][2][6][16][16];  // 12 KB
    __shared__ s16x8 Wl[2][8][32];                                // 8 KB
    __shared__ float bs[2][NH];                                   // 1 KB

    int tid = threadIdx.x;
    for (int t = tid; t < NT1 * NT1; t += 256) Ts[t] = T[t];

    // B-fragments scaled by -log2(e); col mapping global_col = ht*16 + c
    for (int slot = tid; slot < 2 * 8 * 32; slot += 256) {
        int lane_in = slot & 31;
        int frag = slot >> 5;
        int fqk = frag >> 3, fht = frag & 7;
        const float* W = fqk ? Wk : Wq;
        int k0 = (lane_in >> 4) * 8, fcol = lane_in & 15;
        s16x8 v;
#pragma unroll
        for (int i = 0; i < 8; ++i)
            v[i] = (short)f2bf(NLOG2E * W[(k0 + i) * NH + fht * 16 + fcol]);
        Wl[fqk][fht][lane_in] = v;
    }
    if (tid < NH) bs[0][tid] = NLOG2E * bq[tid];
    else bs[1][tid - NH] = NLOG2E * bk[tid - NH];

    int w = tid >> 6, lane = tid & 63;
    int gh = w >> 1, sub = w & 1;

    __syncthreads();   // Ts/Wl/bs ready

#pragma unroll
    for (int it = 0; it < 2; ++it) {
        int grp = it * 2048 + blockIdx.x * 2 + gh;   // 4096 groups total
        int bn0 = grp * 16;
        int n0 = bn0 & (NN - 1);
        bool interior = (n0 != 0) && (n0 != NN - 16);

        if (interior) phaseA<true>(bn0, n0, gh, sub, lane, vg, u, Ts, As);
        else          phaseA<false>(bn0, n0, gh, sub, lane, vg, u, Ts, As);

        __syncthreads();   // As ready

        float* out = sub ? outk : outq;
        if (interior) phaseB<true>(bn0, n0, gh, sub, lane, xs, As, Wl, bs, out);
        else          phaseB<false>(bn0, n0, gh, sub, lane, xs, As, Wl, bs, out);

        __syncthreads();   // As consumed; safe to overwrite next iteration
    }
}

extern "C" void kernel_launch(void* const* d_in, const int* in_sizes, int n_in,
                              void* d_out, int out_size, void* d_ws, size_t ws_size,
                              hipStream_t stream) {
    const float* xs   = (const float*)d_in[0];
    const float* vec  = (const float*)d_in[1];
    const float* Wg   = (const float*)d_in[2];
    const float* qw1  = (const float*)d_in[3];
    const float* qb1  = (const float*)d_in[4];
    const float* qw2  = (const float*)d_in[5];
    const float* qb2  = (const float*)d_in[6];
    const float* kw1  = (const float*)d_in[7];
    const float* kb1  = (const float*)d_in[8];
    const float* kw2  = (const float*)d_in[9];
    const float* kb2  = (const float*)d_in[10];
    const float* Wq   = (const float*)d_in[11];
    const float* bq   = (const float*)d_in[12];
    const float* Wk   = (const float*)d_in[13];
    const float* bk   = (const float*)d_in[14];

    size_t vg_f = (size_t)NB * NN * 48;
    float* vg = (float*)d_ws;
    float* u  = vg + vg_f;
    unsigned* T = (unsigned*)(u + vg_f);
    float* outq = (float*)d_out;
    float* outk = outq + (size_t)NB * NN * NH;

    k_table<<<dim3((NT1 * NT1 + 255) / 256), dim3(256), 0, stream>>>(
        qw1, qb1, qw2, qb2, kw1, kb1, kw2, kb2, T);
    k_vecgeom<<<dim3(3072), dim3(256), 0, stream>>>(vec, Wg, vg);
    k_u<<<dim3(4096), dim3(256), 0, stream>>>(vg, u);
    k_main<<<dim3(1024), dim3(256), 0, stream>>>(
        vg, u, xs, T, Wq, bq, Wk, bk, outq, outk);
}